// Round 5
// baseline (582.913 us; speedup 1.0000x reference)
//
#include <hip/hip_runtime.h>
#include <math.h>

// Problem constants
#define BB 8
#define NN 8192
#define SS 1024
#define NS 32      // nsample
#define DD 64      // point feature channels
#define C1 128     // layer-1 out
#define C2 256     // layer-2 out
#define R2 0.04f   // radius^2

__device__ __forceinline__ float silu_f(float x) {
    return x / (1.0f + __expf(-x));
}

// ---------------------------------------------------------------------------
// K1: query_ball_point. One wave (64 lanes) per center. Scan j ascending,
// collect first 32 in-range indices via ballot + prefix-popcount (preserves
// index order == reference's sort-then-truncate). Pad with first hit.
// Distance formula replicates the reference exactly (no FMA contraction).
// ---------------------------------------------------------------------------
__global__ __launch_bounds__(256) void qbp_kernel(const float* __restrict__ xyz,
                                                  int* __restrict__ idx_ws) {
    int gwave = (blockIdx.x * blockDim.x + threadIdx.x) >> 6;
    int lane  = threadIdx.x & 63;
    int b = gwave >> 10;          // S=1024 centers per batch
    int s = gwave & (SS - 1);
    const float* x = xyz + (size_t)b * 2 * NN;
    const float* y = x + NN;
    float cx = x[s], cy = y[s];
    float cs = __fadd_rn(__fmul_rn(cx, cx), __fmul_rn(cy, cy));
    int* ob = idx_ws + ((size_t)(b * SS + s)) * NS;

    int written = 0;
    int first = -1;
    for (int base = 0; base < NN && written < NS; base += 64) {
        int j = base + lane;
        float px = x[j], py = y[j];
        float pp = __fadd_rn(__fmul_rn(px, px), __fmul_rn(py, py));
        float e  = __fadd_rn(__fmul_rn(cx, px), __fmul_rn(cy, py));
        float d  = __fadd_rn(__fadd_rn(__fmul_rn(-2.0f, e), cs), pp);
        bool in = !(d > R2);                 // reference: excluded iff sqd > r^2
        unsigned long long m = __ballot(in);
        if (first < 0 && m)
            first = base + (__ffsll(m) - 1); // wave-uniform
        int pos = __popcll(m & ((1ull << lane) - 1ull));
        if (in && written + pos < NS) ob[written + pos] = j;
        written += __popcll(m);
        if (written > NS) written = NS;
    }
    // pad remaining slots with the first in-range index (always exists: self)
    if (lane >= written && lane < NS) ob[lane] = first;
}

// ---------------------------------------------------------------------------
// K2: P1[b][j][o] = b1[o] + sum_c W1[o][2+c] * points[b][c][j]
// Point-major layout so the main kernel's gather is 512 contiguous bytes.
// ---------------------------------------------------------------------------
__global__ __launch_bounds__(256) void p1_kernel(const float* __restrict__ points,
                                                 const float* __restrict__ W1,
                                                 const float* __restrict__ b1,
                                                 float* __restrict__ P1) {
    __shared__ float tile[DD][64];
    int bidx = blockIdx.x;        // BB * (NN/64)
    int b  = bidx >> 7;           // NN/64 = 128 tiles per batch
    int j0 = (bidx & 127) << 6;
    int t = threadIdx.x;
    const float* pb = points + (size_t)b * DD * NN;
    #pragma unroll
    for (int i = 0; i < (DD * 64) / 256; ++i) {   // 16 iters
        int e = t + i * 256;
        int c = e >> 6, j = e & 63;
        tile[c][j] = pb[(size_t)c * NN + j0 + j];
    }
    __syncthreads();

    int j  = t & 63;
    int og = t >> 6;              // wave-uniform 0..3
    float rc[DD];
    #pragma unroll
    for (int c = 0; c < DD; ++c) rc[c] = tile[c][j];

    float* outp = P1 + ((size_t)(b * NN + j0 + j)) * C1;
    for (int oi = 0; oi < 32; ++oi) {
        int o = og * 32 + oi;
        const float* w = W1 + o * 66 + 2;
        float acc = b1[o];
        #pragma unroll
        for (int c = 0; c < DD; ++c) acc = fmaf(w[c], rc[c], acc);
        outp[o] = acc;
    }
}

// ---------------------------------------------------------------------------
// K3: fused gather + layer1 (add dxy term, silu) + layer2 + silu + mean.
// One block per center. H1 (32x128 f32) in LDS. Each thread owns one of the
// 256 output channels; 32 accumulators in registers => W2 row read once.
// H1 LDS reads are same-address broadcasts (conflict-free).
// Writes [b][s][o] to tmp (coalesced; K4 transposes) when use_tmp != 0.
// ---------------------------------------------------------------------------
__global__ __launch_bounds__(256) void fused_kernel(const float* __restrict__ xyz,
                                                    const float* __restrict__ W1,
                                                    const float* __restrict__ W2,
                                                    const float* __restrict__ b2,
                                                    const float* __restrict__ P1,
                                                    const int* __restrict__ idx_ws,
                                                    float* __restrict__ tmp,
                                                    float* __restrict__ out,
                                                    int use_tmp) {
    __shared__ float H1s[NS][C1];   // 16 KB
    __shared__ int   idxs[NS];
    __shared__ float dxs[NS], dys[NS];

    int bid = blockIdx.x;
    int b = bid >> 10, s = bid & (SS - 1);
    int t = threadIdx.x;
    const float* x = xyz + (size_t)b * 2 * NN;
    const float* y = x + NN;
    const int* ib = idx_ws + (size_t)(b * SS + s) * NS;

    if (t < NS) {
        int j = ib[t];
        idxs[t] = j;
        float cx = x[s], cy = y[s];
        dxs[t] = x[j] - cx;
        dys[t] = y[j] - cy;
    }
    __syncthreads();

    const float* P1b = P1 + (size_t)b * NN * C1;
    #pragma unroll
    for (int i = 0; i < (NS * C1) / 256; ++i) {   // 16 iters
        int e = t + i * 256;
        int k = e >> 7, c = e & 127;              // c = layer-1 output channel
        int j = idxs[k];
        float v = P1b[(size_t)j * C1 + c];
        v = fmaf(W1[c * 66 + 0], dxs[k], v);
        v = fmaf(W1[c * 66 + 1], dys[k], v);
        H1s[k][c] = silu_f(v);
    }
    __syncthreads();

    int o = t;                                    // output channel
    const float4* w4 = (const float4*)(W2 + (size_t)o * C1);
    const float4* h4 = (const float4*)(&H1s[0][0]);
    float z[NS];
    #pragma unroll
    for (int k = 0; k < NS; ++k) z[k] = 0.0f;

    for (int cb = 0; cb < C1 / 4; ++cb) {
        float4 w = w4[cb];
        #pragma unroll
        for (int k = 0; k < NS; ++k) {
            float4 h = h4[k * (C1 / 4) + cb];
            z[k] = fmaf(w.x, h.x, z[k]);
            z[k] = fmaf(w.y, h.y, z[k]);
            z[k] = fmaf(w.z, h.z, z[k]);
            z[k] = fmaf(w.w, h.w, z[k]);
        }
    }
    float bb = b2[o];
    float acc = 0.0f;
    #pragma unroll
    for (int k = 0; k < NS; ++k) acc += silu_f(z[k] + bb);
    float res = acc * (1.0f / 32.0f);
    if (use_tmp)
        tmp[((size_t)(b * SS + s)) * C2 + o] = res;       // coalesced
    else
        out[((size_t)b * C2 + o) * SS + s] = res;         // strided fallback
}

// ---------------------------------------------------------------------------
// K4: transpose tmp[b][s][o] -> out[b][o][s]. 32x32 LDS tiles, +1 pad.
// ---------------------------------------------------------------------------
__global__ __launch_bounds__(256) void transpose_kernel(const float* __restrict__ tmp,
                                                        float* __restrict__ out) {
    __shared__ float tile[32][33];
    int bid = blockIdx.x;           // BB * (SS/32) * (C2/32) = 8*32*8 = 2048
    int b  = bid >> 8;
    int r  = bid & 255;
    int s0 = (r >> 3) << 5;         // 32 s-tiles per batch
    int o0 = (r & 7) << 5;          // 8 o-tiles per batch
    int t = threadIdx.x;
    int c = t & 31, rr = t >> 5;    // 8 rows per pass, 4 passes
    const float* tb = tmp + (size_t)b * SS * C2;
    #pragma unroll
    for (int i = 0; i < 4; ++i) {
        int row = rr + i * 8;
        tile[row][c] = tb[(size_t)(s0 + row) * C2 + o0 + c];   // coalesced in o
    }
    __syncthreads();
    float* ob = out + (size_t)b * C2 * SS;
    #pragma unroll
    for (int i = 0; i < 4; ++i) {
        int row = rr + i * 8;       // o index within tile
        ob[(size_t)(o0 + row) * SS + s0 + c] = tile[c][row];   // coalesced in s
    }
}

// ---------------------------------------------------------------------------
extern "C" void kernel_launch(void* const* d_in, const int* in_sizes, int n_in,
                              void* d_out, int out_size, void* d_ws, size_t ws_size,
                              hipStream_t stream) {
    const float* xyz    = (const float*)d_in[0];
    const float* points = (const float*)d_in[1];
    const float* W1     = (const float*)d_in[2];
    const float* b1     = (const float*)d_in[3];
    const float* W2     = (const float*)d_in[4];
    const float* b2     = (const float*)d_in[5];
    float* out = (float*)d_out;

    // workspace layout:
    //   idx : 8*1024*32 int            =  1 MB   (offset 0)
    //   P1  : 8*8192*128 f32           = 33.5 MB (offset 1 MB)
    //   tmp : 8*1024*256 f32           =  8.4 MB (offset 1 MB + 33.5 MB)
    const size_t OFF_P1  = (size_t)1 << 20;
    const size_t OFF_TMP = OFF_P1 + (size_t)BB * NN * C1 * sizeof(float);
    const size_t NEED    = OFF_TMP + (size_t)BB * SS * C2 * sizeof(float);

    int*   idx_ws = (int*)d_ws;
    float* P1     = (float*)((char*)d_ws + OFF_P1);
    float* tmp    = (float*)((char*)d_ws + OFF_TMP);
    int use_tmp   = (ws_size >= NEED) ? 1 : 0;

    qbp_kernel  <<<BB * SS / 4,    256, 0, stream>>>(xyz, idx_ws);
    p1_kernel   <<<BB * (NN / 64), 256, 0, stream>>>(points, W1, b1, P1);
    fused_kernel<<<BB * SS,        256, 0, stream>>>(xyz, W1, W2, b2, P1, idx_ws,
                                                     tmp, out, use_tmp);
    if (use_tmp)
        transpose_kernel<<<BB * (SS / 32) * (C2 / 32), 256, 0, stream>>>(tmp, out);
}

// Round 6
// 275.474 us; speedup vs baseline: 2.1160x; 2.1160x over previous
//
#include <hip/hip_runtime.h>
#include <math.h>

// Problem constants
#define BB 8
#define NN 8192
#define SS 1024
#define NS 32      // nsample
#define DD 64      // point feature channels
#define C1 128     // layer-1 out
#define C2 256     // layer-2 out
#define R2 0.04f   // radius^2
#define CPB 8      // centers per block in fused2

using bf16x8 = __attribute__((ext_vector_type(8))) short;
using f32x4  = __attribute__((ext_vector_type(4))) float;

__device__ __forceinline__ float silu_f(float x) {
    return x / (1.0f + __expf(-x));
}
// f32 -> bf16 (RTN-even), returns in low 16 bits
__device__ __forceinline__ unsigned int f2bf(float f) {
    unsigned int u = __float_as_uint(f);
    u += 0x7fffu + ((u >> 16) & 1u);
    return u >> 16;
}
__device__ __forceinline__ float bfl(unsigned int u) { return __uint_as_float(u << 16); }
__device__ __forceinline__ float bfh(unsigned int u) { return __uint_as_float(u & 0xffff0000u); }

// ---------------------------------------------------------------------------
// K1: query_ball_point (UNCHANGED — verified round 5, absmax 3.9e-3).
// ---------------------------------------------------------------------------
__global__ __launch_bounds__(256) void qbp_kernel(const float* __restrict__ xyz,
                                                  int* __restrict__ idx_ws) {
    int gwave = (blockIdx.x * blockDim.x + threadIdx.x) >> 6;
    int lane  = threadIdx.x & 63;
    int b = gwave >> 10;
    int s = gwave & (SS - 1);
    const float* x = xyz + (size_t)b * 2 * NN;
    const float* y = x + NN;
    float cx = x[s], cy = y[s];
    float cs = __fadd_rn(__fmul_rn(cx, cx), __fmul_rn(cy, cy));
    int* ob = idx_ws + ((size_t)(b * SS + s)) * NS;

    int written = 0;
    int first = -1;
    for (int base = 0; base < NN && written < NS; base += 64) {
        int j = base + lane;
        float px = x[j], py = y[j];
        float pp = __fadd_rn(__fmul_rn(px, px), __fmul_rn(py, py));
        float e  = __fadd_rn(__fmul_rn(cx, px), __fmul_rn(cy, py));
        float d  = __fadd_rn(__fadd_rn(__fmul_rn(-2.0f, e), cs), pp);
        bool in = !(d > R2);
        unsigned long long m = __ballot(in);
        if (first < 0 && m)
            first = base + (__ffsll(m) - 1);
        int pos = __popcll(m & ((1ull << lane) - 1ull));
        if (in && written + pos < NS) ob[written + pos] = j;
        written += __popcll(m);
        if (written > NS) written = NS;
    }
    if (lane >= written && lane < NS) ob[lane] = first;
}

// ---------------------------------------------------------------------------
// K2: P1[b][j][o] = b1[o] + sum_c W1[o][2+c] * points[b][c][j], stored BF16
// (pairs packed in uint). Point-major so fused2's gather is 256B/sample.
// ---------------------------------------------------------------------------
__global__ __launch_bounds__(256) void p1_kernel(const float* __restrict__ points,
                                                 const float* __restrict__ W1,
                                                 const float* __restrict__ b1,
                                                 unsigned short* __restrict__ P1) {
    __shared__ float tile[DD][64];
    int bidx = blockIdx.x;        // BB * (NN/64)
    int b  = bidx >> 7;
    int j0 = (bidx & 127) << 6;
    int t = threadIdx.x;
    const float* pb = points + (size_t)b * DD * NN;
    #pragma unroll
    for (int i = 0; i < (DD * 64) / 256; ++i) {
        int e = t + i * 256;
        int c = e >> 6, j = e & 63;
        tile[c][j] = pb[(size_t)c * NN + j0 + j];
    }
    __syncthreads();

    int j  = t & 63;
    int og = t >> 6;              // wave-uniform 0..3
    float rc[DD];
    #pragma unroll
    for (int c = 0; c < DD; ++c) rc[c] = tile[c][j];

    unsigned int* outp = (unsigned int*)(P1 + ((size_t)(b * NN + j0 + j)) * C1);
    for (int oi = 0; oi < 16; ++oi) {     // pairs of output channels
        int o = og * 32 + oi * 2;
        const float* w0 = W1 + (size_t)o * 66 + 2;
        const float* w1r = W1 + (size_t)(o + 1) * 66 + 2;
        float a0 = b1[o], a1 = b1[o + 1];
        #pragma unroll
        for (int c = 0; c < DD; ++c) {
            a0 = fmaf(w0[c], rc[c], a0);
            a1 = fmaf(w1r[c], rc[c], a1);
        }
        outp[og * 16 + oi] = f2bf(a0) | (f2bf(a1) << 16);
    }
}

// ---------------------------------------------------------------------------
// K2b: pack W2 (fp32 [256][128]) into bf16 MFMA B-fragment order.
// Fragment (kb,nt): lane l, elem j supplies B[k=kb*32+8*(l>>4)+j][n=nt*16+(l&15)]
// = W2[n][k]. Stored so each lane's 8 bf16 are one contiguous 16B chunk.
// ---------------------------------------------------------------------------
__global__ __launch_bounds__(256) void w2pack_kernel(const float* __restrict__ W2,
                                                     unsigned short* __restrict__ W2p) {
    int tid = blockIdx.x * 256 + threadIdx.x;   // 0..4095
    int l = tid & 63, frag = tid >> 6;          // frag = kb*16+nt
    int kb = frag >> 4, nt = frag & 15;
    int o  = nt * 16 + (l & 15);
    int c0 = kb * 32 + ((l >> 4) << 3);
    const float* src = W2 + (size_t)o * C1 + c0;
    unsigned int up[4];
    #pragma unroll
    for (int q = 0; q < 4; ++q)
        up[q] = f2bf(src[2 * q]) | (f2bf(src[2 * q + 1]) << 16);
    *(uint4*)(W2p + ((size_t)tid << 3)) = make_uint4(up[0], up[1], up[2], up[3]);
}

// ---------------------------------------------------------------------------
// K3: fused gather + layer1 + silu + MFMA layer2 + silu + mean.
// Block = 256 thr (4 waves) handles CPB=8 centers. Per center:
//   stage: H1 (32x128 bf16) -> LDS, XOR-swizzled (byte ^= (row&7)<<4) so the
//          A-fragment ds_read_b128 (16 lanes @ 256B row stride) is ~2-way.
//   MFMA:  C[32x256] = H1 x W2^T via 2(M) x 16(N) x 4(K) mfma_f32_16x16x32_bf16;
//          wave w owns o in [w*64, w*64+64). W2 frags live in 64 VGPRs, loaded
//          once per block and reused for all 8 centers.
//   epi:   silu(z+b2), mean over 32 rows = lane-local sum of 8 C-regs
//          (row=mt*16+4*(l>>4)+r, col=l&15) + shfl_xor 16/32 across groups.
// k-ordering: contiguous k=8*(lane>>4)+j on BOTH A and B (k-symmetric layout
// makes any consistent ordering correct; C/D map is the HW-verified one).
// ---------------------------------------------------------------------------
__global__ __launch_bounds__(256) void fused2_kernel(const float* __restrict__ xyz,
                                                     const float* __restrict__ W1,
                                                     const float* __restrict__ b2,
                                                     const unsigned short* __restrict__ P1,
                                                     const int* __restrict__ idx_ws,
                                                     const unsigned short* __restrict__ W2p,
                                                     float* __restrict__ tmp) {
    __shared__ __align__(16) unsigned short H1s[NS * C1];   // 8 KB
    __shared__ int   idxs[CPB][NS];
    __shared__ float dxs[CPB][NS], dys[CPB][NS];
    __shared__ float w1xy[2][C1];

    const int t = threadIdx.x;
    const int w = t >> 6, l = t & 63;
    const int gc0 = blockIdx.x * CPB;

    if (t < C1) { w1xy[0][t] = W1[(size_t)t * 66 + 0]; w1xy[1][t] = W1[(size_t)t * 66 + 1]; }
    {
        int ci = t >> 5, kk = t & 31;            // 8 centers x 32 samples = 256
        int gc = gc0 + ci;
        int b = gc >> 10, s = gc & (SS - 1);
        const float* x = xyz + (size_t)b * 2 * NN;
        const float* y = x + NN;
        int j = idx_ws[(size_t)gc * NS + kk];
        idxs[ci][kk] = j;
        dxs[ci][kk] = x[j] - x[s];
        dys[ci][kk] = y[j] - y[s];
    }

    // W2 B-fragments: [ntl][kb], 64 VGPRs, block-invariant.
    bf16x8 bfr[4][4];
    #pragma unroll
    for (int kb = 0; kb < 4; ++kb)
        #pragma unroll
        for (int ntl = 0; ntl < 4; ++ntl) {
            int nt = w * 4 + ntl;
            bfr[ntl][kb] = *(const bf16x8*)(W2p + ((size_t)((kb * 16 + nt) * 64 + l) << 3));
        }
    float b2v[4];
    #pragma unroll
    for (int ntl = 0; ntl < 4; ++ntl) b2v[ntl] = b2[w * 64 + ntl * 16 + (l & 15)];

    __syncthreads();

    const int k = t >> 3, cb = t & 7;            // staging roles: sample, c-block
    for (int ci = 0; ci < CPB; ++ci) {
        int gc = gc0 + ci;
        int b = gc >> 10;
        // ---- layer-1 stage: 16 channels per thread ----
        {
            int j = idxs[ci][k];
            float dx = dxs[ci][k], dy = dys[ci][k];
            const uint4* pr = (const uint4*)(P1 + ((size_t)b * NN + j) * C1 + cb * 16);
            uint4 q0 = pr[0], q1 = pr[1];
            float hv[16];
            hv[0]  = bfl(q0.x); hv[1]  = bfh(q0.x);
            hv[2]  = bfl(q0.y); hv[3]  = bfh(q0.y);
            hv[4]  = bfl(q0.z); hv[5]  = bfh(q0.z);
            hv[6]  = bfl(q0.w); hv[7]  = bfh(q0.w);
            hv[8]  = bfl(q1.x); hv[9]  = bfh(q1.x);
            hv[10] = bfl(q1.y); hv[11] = bfh(q1.y);
            hv[12] = bfl(q1.z); hv[13] = bfh(q1.z);
            hv[14] = bfl(q1.w); hv[15] = bfh(q1.w);
            #pragma unroll
            for (int i = 0; i < 16; ++i) {
                int c = cb * 16 + i;
                float v = hv[i] + w1xy[0][c] * dx + w1xy[1][c] * dy;
                hv[i] = silu_f(v);
            }
            unsigned int up[8];
            #pragma unroll
            for (int q = 0; q < 8; ++q)
                up[q] = f2bf(hv[2 * q]) | (f2bf(hv[2 * q + 1]) << 16);
            unsigned int swz = (unsigned)((k & 7) << 4);
            unsigned int a0 = ((unsigned)(k * 256 + cb * 32)) ^ swz;
            unsigned int a1 = ((unsigned)(k * 256 + cb * 32 + 16)) ^ swz;
            *(uint4*)((char*)H1s + a0) = make_uint4(up[0], up[1], up[2], up[3]);
            *(uint4*)((char*)H1s + a1) = make_uint4(up[4], up[5], up[6], up[7]);
        }
        __syncthreads();
        // ---- MFMA: A-frags from LDS (same swizzle), then 32 MFMAs ----
        bf16x8 afr[2][4];
        #pragma unroll
        for (int mt = 0; mt < 2; ++mt)
            #pragma unroll
            for (int kb = 0; kb < 4; ++kb) {
                int m = mt * 16 + (l & 15);
                unsigned int addr = ((unsigned)(m * 256 + kb * 64 + ((l >> 4) << 4)))
                                    ^ ((unsigned)((m & 7) << 4));
                afr[mt][kb] = *(const bf16x8*)((char*)H1s + addr);
            }
        f32x4 acc[2][4];
        #pragma unroll
        for (int mt = 0; mt < 2; ++mt)
            #pragma unroll
            for (int ntl = 0; ntl < 4; ++ntl) {
                f32x4 z4 = {0.0f, 0.0f, 0.0f, 0.0f};
                acc[mt][ntl] = z4;
            }
        #pragma unroll
        for (int kb = 0; kb < 4; ++kb)
            #pragma unroll
            for (int mt = 0; mt < 2; ++mt)
                #pragma unroll
                for (int ntl = 0; ntl < 4; ++ntl)
                    acc[mt][ntl] = __builtin_amdgcn_mfma_f32_16x16x32_bf16(
                        afr[mt][kb], bfr[ntl][kb], acc[mt][ntl], 0, 0, 0);
        // ---- epilogue: silu(z + b2), mean over 32 samples ----
        float po[4];
        #pragma unroll
        for (int ntl = 0; ntl < 4; ++ntl) {
            float sum = 0.0f;
            #pragma unroll
            for (int mt = 0; mt < 2; ++mt)
                #pragma unroll
                for (int r = 0; r < 4; ++r)
                    sum += silu_f(acc[mt][ntl][r] + b2v[ntl]);
            sum += __shfl_xor(sum, 16);
            sum += __shfl_xor(sum, 32);
            po[ntl] = sum * (1.0f / 32.0f);
        }
        if (l < 16) {
            #pragma unroll
            for (int ntl = 0; ntl < 4; ++ntl)
                tmp[(size_t)gc * C2 + w * 64 + ntl * 16 + l] = po[ntl];
        }
        __syncthreads();   // protect H1s before next center's stage
    }
}

// ---------------------------------------------------------------------------
// K4: transpose tmp[b][s][o] -> out[b][o][s]. 32x32 LDS tiles, +1 pad.
// ---------------------------------------------------------------------------
__global__ __launch_bounds__(256) void transpose_kernel(const float* __restrict__ tmp,
                                                        float* __restrict__ out) {
    __shared__ float tile[32][33];
    int bid = blockIdx.x;
    int b  = bid >> 8;
    int r  = bid & 255;
    int s0 = (r >> 3) << 5;
    int o0 = (r & 7) << 5;
    int t = threadIdx.x;
    int c = t & 31, rr = t >> 5;
    const float* tb = tmp + (size_t)b * SS * C2;
    #pragma unroll
    for (int i = 0; i < 4; ++i) {
        int row = rr + i * 8;
        tile[row][c] = tb[(size_t)(s0 + row) * C2 + o0 + c];
    }
    __syncthreads();
    float* ob = out + (size_t)b * C2 * SS;
    #pragma unroll
    for (int i = 0; i < 4; ++i) {
        int row = rr + i * 8;
        ob[(size_t)(o0 + row) * SS + s0 + c] = tile[c][row];
    }
}

// ---------------------------------------------------------------------------
extern "C" void kernel_launch(void* const* d_in, const int* in_sizes, int n_in,
                              void* d_out, int out_size, void* d_ws, size_t ws_size,
                              hipStream_t stream) {
    const float* xyz    = (const float*)d_in[0];
    const float* points = (const float*)d_in[1];
    const float* W1     = (const float*)d_in[2];
    const float* b1     = (const float*)d_in[3];
    const float* W2     = (const float*)d_in[4];
    const float* b2     = (const float*)d_in[5];
    float* out = (float*)d_out;

    // workspace layout (total 26.3 MB; round-5 pass proves ws >= 34.55 MB):
    //   W2p : 64 KB  bf16 fragment-packed W2        (offset 0)
    //   idx : 1 MB   8*1024*32 int                  (offset 64 KB)
    //   P1  : 16.8 MB 8*8192*128 bf16               (offset 64 KB + 1 MB)
    //   tmp : 8.4 MB  8*1024*256 f32 [b][s][o]      (after P1)
    const size_t OFF_IDX = 65536;
    const size_t OFF_P1  = OFF_IDX + (size_t)BB * SS * NS * sizeof(int);
    const size_t OFF_TMP = OFF_P1 + (size_t)BB * NN * C1 * sizeof(unsigned short);

    unsigned short* W2p = (unsigned short*)d_ws;
    int*            idx = (int*)((char*)d_ws + OFF_IDX);
    unsigned short* P1  = (unsigned short*)((char*)d_ws + OFF_P1);
    float*          tmp = (float*)((char*)d_ws + OFF_TMP);

    qbp_kernel   <<<BB * SS / 4,    256, 0, stream>>>(xyz, idx);
    p1_kernel    <<<BB * (NN / 64), 256, 0, stream>>>(points, W1, b1, P1);
    w2pack_kernel<<<16,             256, 0, stream>>>(W2, W2p);
    fused2_kernel<<<BB * SS / CPB,  256, 0, stream>>>(xyz, W1, b2, P1, idx, W2p, tmp);
    transpose_kernel<<<BB * (SS / 32) * (C2 / 32), 256, 0, stream>>>(tmp, out);
}

// Round 9
// 187.680 us; speedup vs baseline: 3.1059x; 1.4678x over previous
//
#include <hip/hip_runtime.h>
#include <math.h>

// Problem constants
#define BB 8
#define NN 8192
#define SS 1024
#define NS 32      // nsample
#define DD 64      // point feature channels
#define C1 128     // layer-1 out
#define C2 256     // layer-2 out
#define R2 0.04f   // radius^2
#define CPB 8      // centers per block in fused2

using bf16x8 = __attribute__((ext_vector_type(8))) short;
using f32x4  = __attribute__((ext_vector_type(4))) float;

__device__ __forceinline__ float silu_f(float x) {
    return x / (1.0f + __expf(-x));
}
// f32 -> bf16 (RTN-even), returns in low 16 bits
__device__ __forceinline__ unsigned int f2bf(float f) {
    unsigned int u = __float_as_uint(f);
    u += 0x7fffu + ((u >> 16) & 1u);
    return u >> 16;
}
__device__ __forceinline__ float bfl(unsigned int u) { return __uint_as_float(u << 16); }
__device__ __forceinline__ float bfh(unsigned int u) { return __uint_as_float(u & 0xffff0000u); }

// ---------------------------------------------------------------------------
// K1: query_ball_point, dual-chunk (128 pts/iter halves the serialized
// global-load latency chain). Semantics identical to round-5/6 version:
// ascending scan, first-32 in-range via ballot prefix, pad with first hit.
// ---------------------------------------------------------------------------
__global__ __launch_bounds__(256) void qbp_kernel(const float* __restrict__ xyz,
                                                  int* __restrict__ idx_ws) {
    int gwave = (blockIdx.x * blockDim.x + threadIdx.x) >> 6;
    int lane  = threadIdx.x & 63;
    int b = gwave >> 10;
    int s = gwave & (SS - 1);
    const float* x = xyz + (size_t)b * 2 * NN;
    const float* y = x + NN;
    float cx = x[s], cy = y[s];
    float cs = __fadd_rn(__fmul_rn(cx, cx), __fmul_rn(cy, cy));
    int* ob = idx_ws + ((size_t)(b * SS + s)) * NS;

    int written = 0;
    int first = -1;
    for (int base = 0; base < NN && written < NS; base += 128) {
        int jA = base + lane, jB = base + 64 + lane;
        float pxA = x[jA], pyA = y[jA];
        float pxB = x[jB], pyB = y[jB];
        float ppA = __fadd_rn(__fmul_rn(pxA, pxA), __fmul_rn(pyA, pyA));
        float eA  = __fadd_rn(__fmul_rn(cx, pxA), __fmul_rn(cy, pyA));
        float dA  = __fadd_rn(__fadd_rn(__fmul_rn(-2.0f, eA), cs), ppA);
        float ppB = __fadd_rn(__fmul_rn(pxB, pxB), __fmul_rn(pyB, pyB));
        float eB  = __fadd_rn(__fmul_rn(cx, pxB), __fmul_rn(cy, pyB));
        float dB  = __fadd_rn(__fadd_rn(__fmul_rn(-2.0f, eB), cs), ppB);
        bool inA = !(dA > R2);
        bool inB = !(dB > R2);
        unsigned long long mA = __ballot(inA);
        unsigned long long mB = __ballot(inB);
        if (first < 0) {
            if (mA)      first = base + (__ffsll(mA) - 1);
            else if (mB) first = base + 64 + (__ffsll(mB) - 1);
        }
        unsigned long long below = (1ull << lane) - 1ull;
        int posA = __popcll(mA & below);
        if (inA && written + posA < NS) ob[written + posA] = jA;
        int wA = written + __popcll(mA);
        int posB = __popcll(mB & below);
        if (inB && wA + posB < NS) ob[wA + posB] = jB;
        written = wA + __popcll(mB);
        if (written > NS) written = NS;
    }
    if (lane >= written && lane < NS) ob[lane] = first;
}

// ---------------------------------------------------------------------------
// K2: pack W2 and W1 into bf16 MFMA B-fragment order.
// Blocks 0-15: W2 (64 frags: kb(4) x nt(16)); blocks 16-19: W1 (16 frags:
// kb(2) x nt(8), skipping the 2 xy columns). Fragment (kb,nt): lane l elem e
// = W[n = nt*16+(l&15)][k = kb*32 + 8*(l>>4) + e].
// ---------------------------------------------------------------------------
__global__ __launch_bounds__(256) void pack_kernel(const float* __restrict__ W1,
                                                   const float* __restrict__ W2,
                                                   unsigned short* __restrict__ W1p,
                                                   unsigned short* __restrict__ W2p) {
    int bid = blockIdx.x;
    if (bid < 16) {
        int tid = bid * 256 + threadIdx.x;          // 0..4095
        int l = tid & 63, frag = tid >> 6;          // frag = kb*16+nt
        int kb = frag >> 4, nt = frag & 15;
        int o  = nt * 16 + (l & 15);
        int c0 = kb * 32 + ((l >> 4) << 3);
        const float* src = W2 + (size_t)o * C1 + c0;
        unsigned int up[4];
        #pragma unroll
        for (int q = 0; q < 4; ++q)
            up[q] = f2bf(src[2 * q]) | (f2bf(src[2 * q + 1]) << 16);
        *(uint4*)(W2p + ((size_t)tid << 3)) = make_uint4(up[0], up[1], up[2], up[3]);
    } else {
        int tid = (bid - 16) * 256 + threadIdx.x;   // 0..1023
        int l = tid & 63, frag = tid >> 6;          // frag = kb*8+nt
        int kb = frag >> 3, nt = frag & 7;
        int o  = nt * 16 + (l & 15);
        int c0 = kb * 32 + ((l >> 4) << 3);
        const float* src = W1 + (size_t)o * 66 + 2 + c0;
        unsigned int up[4];
        #pragma unroll
        for (int q = 0; q < 4; ++q)
            up[q] = f2bf(src[2 * q]) | (f2bf(src[2 * q + 1]) << 16);
        *(uint4*)(W1p + ((size_t)tid << 3)) = make_uint4(up[0], up[1], up[2], up[3]);
    }
}

// ---------------------------------------------------------------------------
// K3: P1 = silu-less layer-1 feature part via MFMA:
// P1[b][j][o] = b1[o] + sum_c W1[o][2+c]*points[b][c][j], bf16 output.
// Block: 128 j x 128 o x K=64. 4 waves, wave w owns j-rows [w*32,w*32+32).
// A (points^T, bf16) staged in XOR-swizzled LDS; B = W1p frags in VGPRs;
// C bounced via LDS [128][136] bf16 -> coalesced uint4 stores.
// Swizzle: byte ^= (((jj&7)^((jj>>2)&7))<<4)  (write ~4-way, read ~2-way).
// ---------------------------------------------------------------------------
__global__ __launch_bounds__(256) void p1g_kernel(const float* __restrict__ points,
                                                  const unsigned short* __restrict__ W1p,
                                                  const float* __restrict__ b1,
                                                  unsigned short* __restrict__ P1) {
    __shared__ __align__(16) char lds[34816];  // A: 16KB bf16 [128][64]; then C: [128][136] bf16
    const int t = threadIdx.x;
    const int w = t >> 6, l = t & 63;
    const int bidx = blockIdx.x;               // BB * (NN/128) = 512
    const int b  = bidx >> 6;
    const int j0 = (bidx & 63) << 7;

    // B fragments (W1 packed) + bias
    bf16x8 bfr[8][2];
    #pragma unroll
    for (int nt = 0; nt < 8; ++nt)
        #pragma unroll
        for (int kb = 0; kb < 2; ++kb)
            bfr[nt][kb] = *(const bf16x8*)(W1p + (((size_t)((kb * 8 + nt) * 64 + l)) << 3));
    float b1v[8];
    #pragma unroll
    for (int nt = 0; nt < 8; ++nt) b1v[nt] = b1[nt * 16 + (l & 15)];

    // stage A: points[b][c][j0..j0+128) -> lds bf16 [jj][c], swizzled
    {
        const float* pb = points + (size_t)b * DD * NN + j0;
        int jj0 = (t & 31) * 4;
        #pragma unroll
        for (int i = 0; i < 4; ++i) {
            int c = 2 * ((t >> 5) + i * 8);
            float4 q0 = *(const float4*)(pb + (size_t)c * NN + jj0);
            float4 q1 = *(const float4*)(pb + (size_t)(c + 1) * NN + jj0);
            float a0[4] = {q0.x, q0.y, q0.z, q0.w};
            float a1[4] = {q1.x, q1.y, q1.z, q1.w};
            #pragma unroll
            for (int d = 0; d < 4; ++d) {
                int jj = jj0 + d;
                unsigned int u = f2bf(a0[d]) | (f2bf(a1[d]) << 16);
                unsigned int addr = ((unsigned)(jj * 128 + c * 2))
                                    ^ ((unsigned)((((jj & 7) ^ ((jj >> 2) & 7)) << 4)));
                *(unsigned int*)(lds + addr) = u;
            }
        }
    }
    __syncthreads();

    // A fragments
    bf16x8 afr[2][2];
    #pragma unroll
    for (int mt = 0; mt < 2; ++mt)
        #pragma unroll
        for (int kb = 0; kb < 2; ++kb) {
            int jg = w * 32 + mt * 16 + (l & 15);
            unsigned int addr = ((unsigned)(jg * 128 + kb * 64 + ((l >> 4) << 4)))
                                ^ ((unsigned)((((jg & 7) ^ ((jg >> 2) & 7)) << 4)));
            afr[mt][kb] = *(const bf16x8*)(lds + addr);
        }
    __syncthreads();   // A region dead; C region reuses lds

    f32x4 acc[2][8];
    #pragma unroll
    for (int mt = 0; mt < 2; ++mt)
        #pragma unroll
        for (int nt = 0; nt < 8; ++nt) {
            f32x4 z4 = {0.0f, 0.0f, 0.0f, 0.0f};
            acc[mt][nt] = z4;
        }
    #pragma unroll
    for (int kb = 0; kb < 2; ++kb)
        #pragma unroll
        for (int mt = 0; mt < 2; ++mt)
            #pragma unroll
            for (int nt = 0; nt < 8; ++nt)
                acc[mt][nt] = __builtin_amdgcn_mfma_f32_16x16x32_bf16(
                    afr[mt][kb], bfr[nt][kb], acc[mt][nt], 0, 0, 0);

    // write C (+bias) to lds [128][136] bf16, row stride 272B
    #pragma unroll
    for (int mt = 0; mt < 2; ++mt)
        #pragma unroll
        for (int nt = 0; nt < 8; ++nt) {
            int row0 = w * 32 + mt * 16 + ((l >> 4) << 2);
            int col  = nt * 16 + (l & 15);
            #pragma unroll
            for (int r = 0; r < 4; ++r) {
                float v = acc[mt][nt][r] + b1v[nt];
                *(unsigned short*)(lds + (size_t)(row0 + r) * 272 + col * 2) =
                    (unsigned short)f2bf(v);
            }
        }
    __syncthreads();

    // coalesced copy-out: thread t -> row t>>1, half t&1 (64 bf16 = 128B)
    {
        int row = t >> 1, half = t & 1;
        const char* src = lds + (size_t)row * 272 + half * 128;
        unsigned short* dst = P1 + ((size_t)(b * NN + j0 + row)) * C1 + half * 64;
        #pragma unroll
        for (int i = 0; i < 8; ++i)
            *(uint4*)(dst + i * 8) = *(const uint4*)(src + i * 16);
    }
}

// ---------------------------------------------------------------------------
// K4: fused gather + layer1 xy-term + silu + MFMA layer2 + silu + mean.
// (UNCHANGED from round 6 — verified, absmax 7.8e-3.)
// ---------------------------------------------------------------------------
__global__ __launch_bounds__(256) void fused2_kernel(const float* __restrict__ xyz,
                                                     const float* __restrict__ W1,
                                                     const float* __restrict__ b2,
                                                     const unsigned short* __restrict__ P1,
                                                     const int* __restrict__ idx_ws,
                                                     const unsigned short* __restrict__ W2p,
                                                     float* __restrict__ tmp) {
    __shared__ __align__(16) unsigned short H1s[NS * C1];   // 8 KB
    __shared__ int   idxs[CPB][NS];
    __shared__ float dxs[CPB][NS], dys[CPB][NS];
    __shared__ float w1xy[2][C1];

    const int t = threadIdx.x;
    const int w = t >> 6, l = t & 63;
    const int gc0 = blockIdx.x * CPB;

    if (t < C1) { w1xy[0][t] = W1[(size_t)t * 66 + 0]; w1xy[1][t] = W1[(size_t)t * 66 + 1]; }
    {
        int ci = t >> 5, kk = t & 31;
        int gc = gc0 + ci;
        int b = gc >> 10, s = gc & (SS - 1);
        const float* x = xyz + (size_t)b * 2 * NN;
        const float* y = x + NN;
        int j = idx_ws[(size_t)gc * NS + kk];
        idxs[ci][kk] = j;
        dxs[ci][kk] = x[j] - x[s];
        dys[ci][kk] = y[j] - y[s];
    }

    bf16x8 bfr[4][4];
    #pragma unroll
    for (int kb = 0; kb < 4; ++kb)
        #pragma unroll
        for (int ntl = 0; ntl < 4; ++ntl) {
            int nt = w * 4 + ntl;
            bfr[ntl][kb] = *(const bf16x8*)(W2p + ((size_t)((kb * 16 + nt) * 64 + l) << 3));
        }
    float b2v[4];
    #pragma unroll
    for (int ntl = 0; ntl < 4; ++ntl) b2v[ntl] = b2[w * 64 + ntl * 16 + (l & 15)];

    __syncthreads();

    const int k = t >> 3, cb = t & 7;
    for (int ci = 0; ci < CPB; ++ci) {
        int gc = gc0 + ci;
        int b = gc >> 10;
        {
            int j = idxs[ci][k];
            float dx = dxs[ci][k], dy = dys[ci][k];
            const uint4* pr = (const uint4*)(P1 + ((size_t)b * NN + j) * C1 + cb * 16);
            uint4 q0 = pr[0], q1 = pr[1];
            float hv[16];
            hv[0]  = bfl(q0.x); hv[1]  = bfh(q0.x);
            hv[2]  = bfl(q0.y); hv[3]  = bfh(q0.y);
            hv[4]  = bfl(q0.z); hv[5]  = bfh(q0.z);
            hv[6]  = bfl(q0.w); hv[7]  = bfh(q0.w);
            hv[8]  = bfl(q1.x); hv[9]  = bfh(q1.x);
            hv[10] = bfl(q1.y); hv[11] = bfh(q1.y);
            hv[12] = bfl(q1.z); hv[13] = bfh(q1.z);
            hv[14] = bfl(q1.w); hv[15] = bfh(q1.w);
            #pragma unroll
            for (int i = 0; i < 16; ++i) {
                int c = cb * 16 + i;
                float v = hv[i] + w1xy[0][c] * dx + w1xy[1][c] * dy;
                hv[i] = silu_f(v);
            }
            unsigned int up[8];
            #pragma unroll
            for (int q = 0; q < 8; ++q)
                up[q] = f2bf(hv[2 * q]) | (f2bf(hv[2 * q + 1]) << 16);
            unsigned int swz = (unsigned)((k & 7) << 4);
            unsigned int a0 = ((unsigned)(k * 256 + cb * 32)) ^ swz;
            unsigned int a1 = ((unsigned)(k * 256 + cb * 32 + 16)) ^ swz;
            *(uint4*)((char*)H1s + a0) = make_uint4(up[0], up[1], up[2], up[3]);
            *(uint4*)((char*)H1s + a1) = make_uint4(up[4], up[5], up[6], up[7]);
        }
        __syncthreads();
        bf16x8 afr[2][4];
        #pragma unroll
        for (int mt = 0; mt < 2; ++mt)
            #pragma unroll
            for (int kb = 0; kb < 4; ++kb) {
                int m = mt * 16 + (l & 15);
                unsigned int addr = ((unsigned)(m * 256 + kb * 64 + ((l >> 4) << 4)))
                                    ^ ((unsigned)((m & 7) << 4));
                afr[mt][kb] = *(const bf16x8*)((char*)H1s + addr);
            }
        f32x4 acc[2][4];
        #pragma unroll
        for (int mt = 0; mt < 2; ++mt)
            #pragma unroll
            for (int ntl = 0; ntl < 4; ++ntl) {
                f32x4 z4 = {0.0f, 0.0f, 0.0f, 0.0f};
                acc[mt][ntl] = z4;
            }
        #pragma unroll
        for (int kb = 0; kb < 4; ++kb)
            #pragma unroll
            for (int mt = 0; mt < 2; ++mt)
                #pragma unroll
                for (int ntl = 0; ntl < 4; ++ntl)
                    acc[mt][ntl] = __builtin_amdgcn_mfma_f32_16x16x32_bf16(
                        afr[mt][kb], bfr[ntl][kb], acc[mt][ntl], 0, 0, 0);
        float po[4];
        #pragma unroll
        for (int ntl = 0; ntl < 4; ++ntl) {
            float sum = 0.0f;
            #pragma unroll
            for (int mt = 0; mt < 2; ++mt)
                #pragma unroll
                for (int r = 0; r < 4; ++r)
                    sum += silu_f(acc[mt][ntl][r] + b2v[ntl]);
            sum += __shfl_xor(sum, 16);
            sum += __shfl_xor(sum, 32);
            po[ntl] = sum * (1.0f / 32.0f);
        }
        if (l < 16) {
            #pragma unroll
            for (int ntl = 0; ntl < 4; ++ntl)
                tmp[(size_t)gc * C2 + w * 64 + ntl * 16 + l] = po[ntl];
        }
        __syncthreads();
    }
}

// ---------------------------------------------------------------------------
// K5: transpose tmp[b][s][o] -> out[b][o][s]. (UNCHANGED.)
// ---------------------------------------------------------------------------
__global__ __launch_bounds__(256) void transpose_kernel(const float* __restrict__ tmp,
                                                        float* __restrict__ out) {
    __shared__ float tile[32][33];
    int bid = blockIdx.x;
    int b  = bid >> 8;
    int r  = bid & 255;
    int s0 = (r >> 3) << 5;
    int o0 = (r & 7) << 5;
    int t = threadIdx.x;
    int c = t & 31, rr = t >> 5;
    const float* tb = tmp + (size_t)b * SS * C2;
    #pragma unroll
    for (int i = 0; i < 4; ++i) {
        int row = rr + i * 8;
        tile[row][c] = tb[(size_t)(s0 + row) * C2 + o0 + c];
    }
    __syncthreads();
    float* ob = out + (size_t)b * C2 * SS;
    #pragma unroll
    for (int i = 0; i < 4; ++i) {
        int row = rr + i * 8;
        ob[(size_t)(o0 + row) * SS + s0 + c] = tile[c][row];
    }
}

// ---------------------------------------------------------------------------
extern "C" void kernel_launch(void* const* d_in, const int* in_sizes, int n_in,
                              void* d_out, int out_size, void* d_ws, size_t ws_size,
                              hipStream_t stream) {
    const float* xyz    = (const float*)d_in[0];
    const float* points = (const float*)d_in[1];
    const float* W1     = (const float*)d_in[2];
    const float* b1     = (const float*)d_in[3];
    const float* W2     = (const float*)d_in[4];
    const float* b2     = (const float*)d_in[5];
    float* out = (float*)d_out;

    // workspace layout (total ~26.3 MB; round-5/6 passes prove ws >= 34.55 MB):
    //   W2p : 64 KB   (offset 0)
    //   W1p : 16 KB   (offset 64 KB)
    //   idx : 1 MB    (offset 80 KB)
    //   P1  : 16.8 MB (bf16)
    //   tmp : 8.4 MB  (f32 [b][s][o])
    const size_t OFF_W1P = 65536;
    const size_t OFF_IDX = OFF_W1P + 16384;
    const size_t OFF_P1  = OFF_IDX + (size_t)BB * SS * NS * sizeof(int);
    const size_t OFF_TMP = OFF_P1 + (size_t)BB * NN * C1 * sizeof(unsigned short);

    unsigned short* W2p = (unsigned short*)d_ws;
    unsigned short* W1p = (unsigned short*)((char*)d_ws + OFF_W1P);
    int*            idx = (int*)((char*)d_ws + OFF_IDX);
    unsigned short* P1  = (unsigned short*)((char*)d_ws + OFF_P1);
    float*          tmp = (float*)((char*)d_ws + OFF_TMP);

    qbp_kernel   <<<BB * SS / 4,     256, 0, stream>>>(xyz, idx);
    pack_kernel  <<<20,              256, 0, stream>>>(W1, W2, W1p, W2p);
    p1g_kernel   <<<BB * (NN / 128), 256, 0, stream>>>(points, W1p, b1, P1);
    fused2_kernel<<<BB * SS / CPB,   256, 0, stream>>>(xyz, W1, b2, P1, idx, W2p, tmp);
    transpose_kernel<<<BB * (SS / 32) * (C2 / 32), 256, 0, stream>>>(tmp, out);
}

// Round 10
// 162.563 us; speedup vs baseline: 3.5858x; 1.1545x over previous
//
#include <hip/hip_runtime.h>
#include <math.h>

// Problem constants
#define BB 8
#define NN 8192
#define SS 1024
#define NS 32      // nsample
#define DD 64      // point feature channels
#define C1 128     // layer-1 out
#define C2 256     // layer-2 out
#define R2 0.04f   // radius^2
#define CPB 4      // centers per block in fused2 (r10: 8->4 for occupancy)

using bf16x8 = __attribute__((ext_vector_type(8))) short;
using f32x4  = __attribute__((ext_vector_type(4))) float;

// fast silu: x * rcp(1 + exp2(-x*log2e)) — 5 VALU (2 trans), vs precise-div ~11
__device__ __forceinline__ float rcp_f(float v) {
    float r; asm("v_rcp_f32 %0, %1" : "=v"(r) : "v"(v)); return r;
}
__device__ __forceinline__ float exp2_f(float v) {
    float r; asm("v_exp_f32 %0, %1" : "=v"(r) : "v"(v)); return r;
}
__device__ __forceinline__ float silu_f(float x) {
    return x * rcp_f(1.0f + exp2_f(x * -1.44269504088896f));
}
// f32 -> bf16 (RTN-even), returns in low 16 bits
__device__ __forceinline__ unsigned int f2bf(float f) {
    unsigned int u = __float_as_uint(f);
    u += 0x7fffu + ((u >> 16) & 1u);
    return u >> 16;
}
__device__ __forceinline__ float bfl(unsigned int u) { return __uint_as_float(u << 16); }
__device__ __forceinline__ float bfh(unsigned int u) { return __uint_as_float(u & 0xffff0000u); }

// ---------------------------------------------------------------------------
// K1: query_ball_point, dual-chunk + 1-deep prefetch: next chunk's 4 loads
// issue BEFORE processing the current chunk, hiding the load->ballot->branch
// dependent chain (~300cyc L2) under ~60 VALU ops. Semantics identical to the
// verified r5/r6 scan (ascending order, first-32, pad with first hit).
// ---------------------------------------------------------------------------
__global__ __launch_bounds__(256) void qbp_kernel(const float* __restrict__ xyz,
                                                  int* __restrict__ idx_ws) {
    int gwave = (blockIdx.x * blockDim.x + threadIdx.x) >> 6;
    int lane  = threadIdx.x & 63;
    int b = gwave >> 10;
    int s = gwave & (SS - 1);
    const float* x = xyz + (size_t)b * 2 * NN;
    const float* y = x + NN;
    float cx = x[s], cy = y[s];
    float cs = __fadd_rn(__fmul_rn(cx, cx), __fmul_rn(cy, cy));
    int* ob = idx_ws + ((size_t)(b * SS + s)) * NS;

    // prefetch chunk 0
    float pxA = x[lane],      pyA = y[lane];
    float pxB = x[64 + lane], pyB = y[64 + lane];

    int written = 0;
    int first = -1;
    for (int base = 0; base < NN && written < NS; base += 128) {
        // issue next chunk's loads (clamped; unused on last/early-exit iter)
        int jA2 = base + 128 + lane;      if (jA2 >= NN) jA2 = NN - 1;
        int jB2 = base + 192 + lane;      if (jB2 >= NN) jB2 = NN - 1;
        float nxA = x[jA2], nyA = y[jA2];
        float nxB = x[jB2], nyB = y[jB2];

        // process current chunk (exact reference arithmetic)
        float ppA = __fadd_rn(__fmul_rn(pxA, pxA), __fmul_rn(pyA, pyA));
        float eA  = __fadd_rn(__fmul_rn(cx, pxA), __fmul_rn(cy, pyA));
        float dA  = __fadd_rn(__fadd_rn(__fmul_rn(-2.0f, eA), cs), ppA);
        float ppB = __fadd_rn(__fmul_rn(pxB, pxB), __fmul_rn(pyB, pyB));
        float eB  = __fadd_rn(__fmul_rn(cx, pxB), __fmul_rn(cy, pyB));
        float dB  = __fadd_rn(__fadd_rn(__fmul_rn(-2.0f, eB), cs), ppB);
        bool inA = !(dA > R2);
        bool inB = !(dB > R2);
        unsigned long long mA = __ballot(inA);
        unsigned long long mB = __ballot(inB);
        if (first < 0) {
            if (mA)      first = base + (__ffsll(mA) - 1);
            else if (mB) first = base + 64 + (__ffsll(mB) - 1);
        }
        unsigned long long below = (1ull << lane) - 1ull;
        int posA = __popcll(mA & below);
        if (inA && written + posA < NS) ob[written + posA] = base + lane;
        int wA = written + __popcll(mA);
        int posB = __popcll(mB & below);
        if (inB && wA + posB < NS) ob[wA + posB] = base + 64 + lane;
        written = wA + __popcll(mB);
        if (written > NS) written = NS;

        pxA = nxA; pyA = nyA; pxB = nxB; pyB = nyB;
    }
    if (lane >= written && lane < NS) ob[lane] = first;
}

// ---------------------------------------------------------------------------
// K2: pack W2 and W1 into bf16 MFMA B-fragment order. (UNCHANGED, verified.)
// ---------------------------------------------------------------------------
__global__ __launch_bounds__(256) void pack_kernel(const float* __restrict__ W1,
                                                   const float* __restrict__ W2,
                                                   unsigned short* __restrict__ W1p,
                                                   unsigned short* __restrict__ W2p) {
    int bid = blockIdx.x;
    if (bid < 16) {
        int tid = bid * 256 + threadIdx.x;          // 0..4095
        int l = tid & 63, frag = tid >> 6;          // frag = kb*16+nt
        int kb = frag >> 4, nt = frag & 15;
        int o  = nt * 16 + (l & 15);
        int c0 = kb * 32 + ((l >> 4) << 3);
        const float* src = W2 + (size_t)o * C1 + c0;
        unsigned int up[4];
        #pragma unroll
        for (int q = 0; q < 4; ++q)
            up[q] = f2bf(src[2 * q]) | (f2bf(src[2 * q + 1]) << 16);
        *(uint4*)(W2p + ((size_t)tid << 3)) = make_uint4(up[0], up[1], up[2], up[3]);
    } else {
        int tid = (bid - 16) * 256 + threadIdx.x;   // 0..1023
        int l = tid & 63, frag = tid >> 6;          // frag = kb*8+nt
        int kb = frag >> 3, nt = frag & 7;
        int o  = nt * 16 + (l & 15);
        int c0 = kb * 32 + ((l >> 4) << 3);
        const float* src = W1 + (size_t)o * 66 + 2 + c0;
        unsigned int up[4];
        #pragma unroll
        for (int q = 0; q < 4; ++q)
            up[q] = f2bf(src[2 * q]) | (f2bf(src[2 * q + 1]) << 16);
        *(uint4*)(W1p + ((size_t)tid << 3)) = make_uint4(up[0], up[1], up[2], up[3]);
    }
}

// ---------------------------------------------------------------------------
// K3: P1 GEMM via MFMA. (UNCHANGED from r9 — verified, ~<20us.)
// ---------------------------------------------------------------------------
__global__ __launch_bounds__(256) void p1g_kernel(const float* __restrict__ points,
                                                  const unsigned short* __restrict__ W1p,
                                                  const float* __restrict__ b1,
                                                  unsigned short* __restrict__ P1) {
    __shared__ __align__(16) char lds[34816];
    const int t = threadIdx.x;
    const int w = t >> 6, l = t & 63;
    const int bidx = blockIdx.x;               // BB * (NN/128) = 512
    const int b  = bidx >> 6;
    const int j0 = (bidx & 63) << 7;

    bf16x8 bfr[8][2];
    #pragma unroll
    for (int nt = 0; nt < 8; ++nt)
        #pragma unroll
        for (int kb = 0; kb < 2; ++kb)
            bfr[nt][kb] = *(const bf16x8*)(W1p + (((size_t)((kb * 8 + nt) * 64 + l)) << 3));
    float b1v[8];
    #pragma unroll
    for (int nt = 0; nt < 8; ++nt) b1v[nt] = b1[nt * 16 + (l & 15)];

    {
        const float* pb = points + (size_t)b * DD * NN + j0;
        int jj0 = (t & 31) * 4;
        #pragma unroll
        for (int i = 0; i < 4; ++i) {
            int c = 2 * ((t >> 5) + i * 8);
            float4 q0 = *(const float4*)(pb + (size_t)c * NN + jj0);
            float4 q1 = *(const float4*)(pb + (size_t)(c + 1) * NN + jj0);
            float a0[4] = {q0.x, q0.y, q0.z, q0.w};
            float a1[4] = {q1.x, q1.y, q1.z, q1.w};
            #pragma unroll
            for (int d = 0; d < 4; ++d) {
                int jj = jj0 + d;
                unsigned int u = f2bf(a0[d]) | (f2bf(a1[d]) << 16);
                unsigned int addr = ((unsigned)(jj * 128 + c * 2))
                                    ^ ((unsigned)((((jj & 7) ^ ((jj >> 2) & 7)) << 4)));
                *(unsigned int*)(lds + addr) = u;
            }
        }
    }
    __syncthreads();

    bf16x8 afr[2][2];
    #pragma unroll
    for (int mt = 0; mt < 2; ++mt)
        #pragma unroll
        for (int kb = 0; kb < 2; ++kb) {
            int jg = w * 32 + mt * 16 + (l & 15);
            unsigned int addr = ((unsigned)(jg * 128 + kb * 64 + ((l >> 4) << 4)))
                                ^ ((unsigned)((((jg & 7) ^ ((jg >> 2) & 7)) << 4)));
            afr[mt][kb] = *(const bf16x8*)(lds + addr);
        }
    __syncthreads();

    f32x4 acc[2][8];
    #pragma unroll
    for (int mt = 0; mt < 2; ++mt)
        #pragma unroll
        for (int nt = 0; nt < 8; ++nt) {
            f32x4 z4 = {0.0f, 0.0f, 0.0f, 0.0f};
            acc[mt][nt] = z4;
        }
    #pragma unroll
    for (int kb = 0; kb < 2; ++kb)
        #pragma unroll
        for (int mt = 0; mt < 2; ++mt)
            #pragma unroll
            for (int nt = 0; nt < 8; ++nt)
                acc[mt][nt] = __builtin_amdgcn_mfma_f32_16x16x32_bf16(
                    afr[mt][kb], bfr[nt][kb], acc[mt][nt], 0, 0, 0);

    #pragma unroll
    for (int mt = 0; mt < 2; ++mt)
        #pragma unroll
        for (int nt = 0; nt < 8; ++nt) {
            int row0 = w * 32 + mt * 16 + ((l >> 4) << 2);
            int col  = nt * 16 + (l & 15);
            #pragma unroll
            for (int r = 0; r < 4; ++r) {
                float v = acc[mt][nt][r] + b1v[nt];
                *(unsigned short*)(lds + (size_t)(row0 + r) * 272 + col * 2) =
                    (unsigned short)f2bf(v);
            }
        }
    __syncthreads();

    {
        int row = t >> 1, half = t & 1;
        const char* src = lds + (size_t)row * 272 + half * 128;
        unsigned short* dst = P1 + ((size_t)(b * NN + j0 + row)) * C1 + half * 64;
        #pragma unroll
        for (int i = 0; i < 8; ++i)
            *(uint4*)(dst + i * 8) = *(const uint4*)(src + i * 16);
    }
}

// ---------------------------------------------------------------------------
// K4: fused gather + layer1 xy-term + silu + MFMA layer2 + silu + mean.
// r10 rewrite: CPB=4, double-buffered H1s (1 barrier/center), T14 split
// (gather for ci+1 issues before MFMA(ci)), w1xy + all LDS addrs hoisted
// out of the center loop, fast rcp/exp2 silu. MFMA layout identical to the
// verified r6/r9 kernel.
// ---------------------------------------------------------------------------
__global__ __launch_bounds__(256) void fused2_kernel(const float* __restrict__ xyz,
                                                     const float* __restrict__ W1,
                                                     const float* __restrict__ b2,
                                                     const unsigned short* __restrict__ P1,
                                                     const int* __restrict__ idx_ws,
                                                     const unsigned short* __restrict__ W2p,
                                                     float* __restrict__ tmp) {
    __shared__ __align__(16) unsigned short H1s[2][NS * C1];   // 2 x 8 KB
    __shared__ int   idxs[CPB][NS];
    __shared__ float dxs[CPB][NS], dys[CPB][NS];
    __shared__ float w1xy[C1][2];

    const int t = threadIdx.x;
    const int w = t >> 6, l = t & 63;
    const int gc0 = blockIdx.x * CPB;
    const int b   = gc0 >> 10;             // CPB divides 1024: block-uniform

    if (t < C1) {
        w1xy[t][0] = W1[(size_t)t * 66 + 0];
        w1xy[t][1] = W1[(size_t)t * 66 + 1];
    }
    if (t < CPB * NS) {                    // 128 threads stage idx/dx/dy
        int ci = t >> 5, kk = t & 31;
        int gc = gc0 + ci;
        int s = gc & (SS - 1);
        const float* x = xyz + (size_t)b * 2 * NN;
        const float* y = x + NN;
        int j = idx_ws[(size_t)gc * NS + kk];
        idxs[ci][kk] = j;
        dxs[ci][kk] = x[j] - x[s];
        dys[ci][kk] = y[j] - y[s];
    }

    // W2 B-fragments (64 VGPR) + bias — block-invariant
    bf16x8 bfr[4][4];
    #pragma unroll
    for (int kb = 0; kb < 4; ++kb)
        #pragma unroll
        for (int ntl = 0; ntl < 4; ++ntl) {
            int nt = w * 4 + ntl;
            bfr[ntl][kb] = *(const bf16x8*)(W2p + ((size_t)((kb * 16 + nt) * 64 + l) << 3));
        }
    float b2v[4];
    #pragma unroll
    for (int ntl = 0; ntl < 4; ++ntl) b2v[ntl] = b2[w * 64 + ntl * 16 + (l & 15)];

    __syncthreads();

    // --- loop-invariant per-thread state, hoisted ---
    const int k = t >> 3, cb = t & 7;      // staging roles: sample, c-block
    float wx[16], wy[16];
    #pragma unroll
    for (int i = 0; i < 16; ++i) {
        wx[i] = w1xy[cb * 16 + i][0];
        wy[i] = w1xy[cb * 16 + i][1];
    }
    const unsigned int swz = (unsigned)((k & 7) << 4);
    const unsigned int sa0 = ((unsigned)(k * 256 + cb * 32)) ^ swz;
    const unsigned int sa1 = ((unsigned)(k * 256 + cb * 32 + 16)) ^ swz;
    unsigned int afr_addr[2][4];
    #pragma unroll
    for (int mt = 0; mt < 2; ++mt)
        #pragma unroll
        for (int kb = 0; kb < 4; ++kb) {
            int m = mt * 16 + (l & 15);
            afr_addr[mt][kb] = ((unsigned)(m * 256 + kb * 64 + ((l >> 4) << 4)))
                               ^ ((unsigned)((m & 7) << 4));
        }
    const unsigned short* P1b = P1 + (size_t)b * NN * C1 + cb * 16;

    // --- software-pipelined center loop: ci=-1 primes buf0 ---
    for (int ci = -1; ci < CPB; ++ci) {
        const bool have = (ci + 1 < CPB);

        // phase 1: issue next center's gather (global loads, latency hidden
        // under phase-2 MFMA/epilogue)
        uint4 q0, q1; float dx = 0.0f, dy = 0.0f;
        if (have) {
            int j = idxs[ci + 1][k];
            dx = dxs[ci + 1][k]; dy = dys[ci + 1][k];
            const uint4* pr = (const uint4*)(P1b + (size_t)j * C1);
            q0 = pr[0]; q1 = pr[1];
        }

        // phase 2: MFMA + epilogue for current center from buf[ci&1]
        if (ci >= 0) {
            const char* bufr = (const char*)H1s[ci & 1];
            bf16x8 afr[2][4];
            #pragma unroll
            for (int mt = 0; mt < 2; ++mt)
                #pragma unroll
                for (int kb = 0; kb < 4; ++kb)
                    afr[mt][kb] = *(const bf16x8*)(bufr + afr_addr[mt][kb]);
            f32x4 acc[2][4];
            #pragma unroll
            for (int mt = 0; mt < 2; ++mt)
                #pragma unroll
                for (int ntl = 0; ntl < 4; ++ntl) {
                    f32x4 z4 = {0.0f, 0.0f, 0.0f, 0.0f};
                    acc[mt][ntl] = z4;
                }
            #pragma unroll
            for (int kb = 0; kb < 4; ++kb)
                #pragma unroll
                for (int mt = 0; mt < 2; ++mt)
                    #pragma unroll
                    for (int ntl = 0; ntl < 4; ++ntl)
                        acc[mt][ntl] = __builtin_amdgcn_mfma_f32_16x16x32_bf16(
                            afr[mt][kb], bfr[ntl][kb], acc[mt][ntl], 0, 0, 0);
            float po[4];
            #pragma unroll
            for (int ntl = 0; ntl < 4; ++ntl) {
                float sum = 0.0f;
                #pragma unroll
                for (int mt = 0; mt < 2; ++mt)
                    #pragma unroll
                    for (int r = 0; r < 4; ++r)
                        sum += silu_f(acc[mt][ntl][r] + b2v[ntl]);
                sum += __shfl_xor(sum, 16);
                sum += __shfl_xor(sum, 32);
                po[ntl] = sum * (1.0f / 32.0f);
            }
            if (l < 16) {
                int gc = gc0 + ci;
                #pragma unroll
                for (int ntl = 0; ntl < 4; ++ntl)
                    tmp[(size_t)gc * C2 + w * 64 + ntl * 16 + l] = po[ntl];
            }
        }

        // phase 3: silu + pack + LDS write for next center into buf[(ci+1)&1]
        if (have) {
            float hv[16];
            hv[0]  = bfl(q0.x); hv[1]  = bfh(q0.x);
            hv[2]  = bfl(q0.y); hv[3]  = bfh(q0.y);
            hv[4]  = bfl(q0.z); hv[5]  = bfh(q0.z);
            hv[6]  = bfl(q0.w); hv[7]  = bfh(q0.w);
            hv[8]  = bfl(q1.x); hv[9]  = bfh(q1.x);
            hv[10] = bfl(q1.y); hv[11] = bfh(q1.y);
            hv[12] = bfl(q1.z); hv[13] = bfh(q1.z);
            hv[14] = bfl(q1.w); hv[15] = bfh(q1.w);
            #pragma unroll
            for (int i = 0; i < 16; ++i) {
                float v = hv[i] + wx[i] * dx + wy[i] * dy;
                hv[i] = silu_f(v);
            }
            unsigned int up[8];
            #pragma unroll
            for (int q = 0; q < 8; ++q)
                up[q] = f2bf(hv[2 * q]) | (f2bf(hv[2 * q + 1]) << 16);
            char* bufw = (char*)H1s[(ci + 1) & 1];
            *(uint4*)(bufw + sa0) = make_uint4(up[0], up[1], up[2], up[3]);
            *(uint4*)(bufw + sa1) = make_uint4(up[4], up[5], up[6], up[7]);
        }
        __syncthreads();
    }
}

// ---------------------------------------------------------------------------
// K5: transpose tmp[b][s][o] -> out[b][o][s]. (UNCHANGED.)
// ---------------------------------------------------------------------------
__global__ __launch_bounds__(256) void transpose_kernel(const float* __restrict__ tmp,
                                                        float* __restrict__ out) {
    __shared__ float tile[32][33];
    int bid = blockIdx.x;
    int b  = bid >> 8;
    int r  = bid & 255;
    int s0 = (r >> 3) << 5;
    int o0 = (r & 7) << 5;
    int t = threadIdx.x;
    int c = t & 31, rr = t >> 5;
    const float* tb = tmp + (size_t)b * SS * C2;
    #pragma unroll
    for (int i = 0; i < 4; ++i) {
        int row = rr + i * 8;
        tile[row][c] = tb[(size_t)(s0 + row) * C2 + o0 + c];
    }
    __syncthreads();
    float* ob = out + (size_t)b * C2 * SS;
    #pragma unroll
    for (int i = 0; i < 4; ++i) {
        int row = rr + i * 8;
        ob[(size_t)(o0 + row) * SS + s0 + c] = tile[c][row];
    }
}

// ---------------------------------------------------------------------------
extern "C" void kernel_launch(void* const* d_in, const int* in_sizes, int n_in,
                              void* d_out, int out_size, void* d_ws, size_t ws_size,
                              hipStream_t stream) {
    const float* xyz    = (const float*)d_in[0];
    const float* points = (const float*)d_in[1];
    const float* W1     = (const float*)d_in[2];
    const float* b1     = (const float*)d_in[3];
    const float* W2     = (const float*)d_in[4];
    const float* b2     = (const float*)d_in[5];
    float* out = (float*)d_out;

    // workspace layout (total ~26.3 MB; r5-r9 passes prove ws >= 34.55 MB):
    const size_t OFF_W1P = 65536;
    const size_t OFF_IDX = OFF_W1P + 16384;
    const size_t OFF_P1  = OFF_IDX + (size_t)BB * SS * NS * sizeof(int);
    const size_t OFF_TMP = OFF_P1 + (size_t)BB * NN * C1 * sizeof(unsigned short);

    unsigned short* W2p = (unsigned short*)d_ws;
    unsigned short* W1p = (unsigned short*)((char*)d_ws + OFF_W1P);
    int*            idx = (int*)((char*)d_ws + OFF_IDX);
    unsigned short* P1  = (unsigned short*)((char*)d_ws + OFF_P1);
    float*          tmp = (float*)((char*)d_ws + OFF_TMP);

    qbp_kernel   <<<BB * SS / 4,     256, 0, stream>>>(xyz, idx);
    pack_kernel  <<<20,              256, 0, stream>>>(W1, W2, W1p, W2p);
    p1g_kernel   <<<BB * (NN / 128), 256, 0, stream>>>(points, W1p, b1, P1);
    fused2_kernel<<<BB * SS / CPB,   256, 0, stream>>>(xyz, W1, b2, P1, idx, W2p, tmp);
    transpose_kernel<<<BB * (SS / 32) * (C2 / 32), 256, 0, stream>>>(tmp, out);
}